// Round 5
// baseline (279.365 us; speedup 1.0000x reference)
//
#include <hip/hip_runtime.h>

#define SEQ 2048
#define DMODEL 1024
#define NH 16
#define DH 64

typedef __attribute__((ext_vector_type(8))) short bf16x8;
typedef __attribute__((ext_vector_type(4))) short bf16x4;
typedef __attribute__((ext_vector_type(4))) float floatx4;
typedef __attribute__((ext_vector_type(4))) unsigned short u16x4;
typedef unsigned short u16;
typedef unsigned int u32;

typedef const void __attribute__((address_space(1)))* as1cvp;
typedef void __attribute__((address_space(3)))* as3vp;

__device__ __forceinline__ void glds16(const void* g, void* l) {
    __builtin_amdgcn_global_load_lds((as1cvp)g, (as3vp)l, 16, 0, 0);
}

// f32->bf16 round-half-up: u + 0x8000, take hi16. Same 0.5-ulp worst case as
// RNE (only exact-tie direction differs -> unbiased for continuous data).
__device__ __forceinline__ u16 f2bf(float f) {
    union { u32 u; float f; } v; v.f = f;
    return (u16)((v.u + 0x8000u) >> 16);
}

// packed f32->2xbf16 half-up: 2 adds + 1 v_perm_b32 (hi16 of each)
__device__ __forceinline__ u32 pk2(float a, float b) {
    union { u32 u; float f; } x, y; x.f = a; y.f = b;
    u32 xr = x.u + 0x8000u, yr = y.u + 0x8000u;
#if __has_builtin(__builtin_amdgcn_perm)
    return __builtin_amdgcn_perm(yr, xr, 0x07060302u);
#else
    return (xr >> 16) | (yr & 0xffff0000u);
#endif
}

// raw v_exp_f32 (= exp2); log2e folded into QSCALE so scores are log2-domain.
__device__ __forceinline__ float ex2(float x) {
#if __has_builtin(__builtin_amdgcn_exp2f)
    return __builtin_amdgcn_exp2f(x);
#else
    float r; asm("v_exp_f32 %0, %1" : "=v"(r) : "v"(x)); return r;
#endif
}

// 16x16x16 bf16 MFMA: B-frag layout k=quad*4+j matches C-layout of S^T
__device__ __forceinline__ floatx4 mfma16(bf16x4 a, bf16x4 b, floatx4 c) {
#if __has_builtin(__builtin_amdgcn_mfma_f32_16x16x16bf16_1k)
    return __builtin_amdgcn_mfma_f32_16x16x16bf16_1k(a, b, c, 0, 0, 0);
#else
    asm volatile("v_mfma_f32_16x16x16_bf16 %0, %1, %2, %0" : "+v"(c) : "v"(a), "v"(b));
    return c;
#endif
}

__device__ __forceinline__ uint4 cvt8(const float* __restrict__ p) {
    float4 a = *(const float4*)p;
    float4 b = *(const float4*)(p + 4);
    uint4 q;
    q.x = pk2(a.x, a.y); q.y = pk2(a.z, a.w);
    q.z = pk2(b.x, b.y); q.w = pk2(b.z, b.w);
    return q;
}

// q pre-scale: 1/sqrt(Dh) * log2(e) -> scores are log2-domain, exp via v_exp_f32
#define QSCALE 0.18033688011112042f

// ---------------- convert Q,K,V + 4 weights to bf16 once ----------------
__global__ __launch_bounds__(256) void cvt_all(
    const float* __restrict__ Q, const float* __restrict__ K, const float* __restrict__ V,
    const float* __restrict__ W0, const float* __restrict__ W1,
    const float* __restrict__ W2, const float* __restrict__ W3,
    u16* __restrict__ Qb, u16* __restrict__ Kb, u16* __restrict__ Vb,
    u16* __restrict__ Wb)
{
    const int y = blockIdx.y;
    const float* src; u16* dst;
    if (y == 0)      { src = Q;  dst = Qb; }
    else if (y == 1) { src = K;  dst = Kb; }
    else if (y == 2) { src = V;  dst = Vb; }
    else {
        if (blockIdx.x >= 512) return;
        src = (y == 3) ? W0 : (y == 4) ? W1 : (y == 5) ? W2 : W3;
        dst = Wb + (size_t)(y - 3) * 1048576;
    }
    size_t i = ((size_t)blockIdx.x * 256 + threadIdx.x) * 8;
    *(uint4*)(dst + i) = cvt8(src + i);
}

__global__ __launch_bounds__(256) void cvt_w(
    const float* __restrict__ W0, const float* __restrict__ W1,
    const float* __restrict__ W2, const float* __restrict__ W3,
    u16* __restrict__ out)
{
    const float* src = (blockIdx.y == 0) ? W0 : (blockIdx.y == 1) ? W1
                     : (blockIdx.y == 2) ? W2 : W3;
    size_t i = ((size_t)blockIdx.x * 256 + threadIdx.x) * 8;
    *(uint4*)(out + (size_t)blockIdx.y * 1048576 + i) = cvt8(src + i);
}

// shared epilogue store for QKV projections (z<2: scalar, z=2: vectorized 8B)
__device__ __forceinline__ void qkv_store(
    int z, u16* __restrict__ outp, int rowg, int col, floatx4 a4, float bv, float sc)
{
    union { u32 w[2]; u16 h[4]; u16x4 v4; } pk;
    pk.w[0] = pk2((a4[0] + bv) * sc, (a4[1] + bv) * sc);
    pk.w[1] = pk2((a4[2] + bv) * sc, (a4[3] + bv) * sc);
    int b = rowg >> 11, s = rowg & 2047, h = col >> 6, d = col & 63;
    if (z < 2) {
#pragma unroll
        for (int r = 0; r < 4; r++)
            outp[((size_t)(b * NH + h) * SEQ + s + r) * DH + d] = pk.h[r];
    } else {
        *(u16x4*)(outp + ((size_t)(b * NH + h) * DH + d) * SEQ + s) = pk.v4;
    }
}

// ---------------- QKV projection v2: 3-buffer LDS pipeline, counted vmcnt ----------------
// r4 theory: old version issued 4 glds16 then __syncthreads -> compiler drains
// vmcnt(0) before s_barrier -> full DMA latency exposed every K-step (~10% MFMA
// util). NB=3 ring: stage(i+2), vmcnt(4) [tile i+1 done, i+2 in flight], RAW
// s_barrier (no implicit drain), compute(i). Writer buf (i+2)%3 never collides
// with concurrent readers' (i)%3 / (i+1)%3 -> single barrier per step is safe.
__global__ __launch_bounds__(256) void gemm_qkv_bb(
    const u16* __restrict__ Qb, const u16* __restrict__ Kb, const u16* __restrict__ Vb,
    const u16* __restrict__ Wb,
    const float* __restrict__ b0, const float* __restrict__ b1, const float* __restrict__ b2,
    u16* __restrict__ qo, u16* __restrict__ ko, u16* __restrict__ vto)
{
    __shared__ __align__(16) u16 As[3][4096];
    __shared__ __align__(16) u16 Bs[3][4096];
    const int tid = threadIdx.x, l = tid & 63, w = tid >> 6;
    const int lm = l & 15, quad = l >> 4;
    const int wr = (w >> 1) * 64, wc = (w & 1) * 64;
    const int bm = blockIdx.y * 128, bn = blockIdx.x * 128;
    const int z = blockIdx.z;
    const u16* A      = (z == 0) ? Qb : (z == 1) ? Kb : Vb;
    const u16* W      = Wb + (size_t)z * 1048576;
    const float* bias = (z == 0) ? b0 : (z == 1) ? b1 : b2;

    const int srow = tid >> 2, scol = (tid & 3) * 8;

    floatx4 acc[4][4];
#pragma unroll
    for (int i = 0; i < 4; i++)
#pragma unroll
        for (int j = 0; j < 4; j++) acc[i][j] = (floatx4){0.f, 0.f, 0.f, 0.f};

#define QKV_STAGE(I, NB) do { \
        const int kt_ = (I) * 32; \
        glds16(A + (size_t)(bm + srow) * DMODEL + kt_ + scol, As[NB] + w * 512); \
        glds16(A + (size_t)(bm + 64 + srow) * DMODEL + kt_ + scol, As[NB] + 2048 + w * 512); \
        glds16(W + (size_t)(bn + srow) * DMODEL + kt_ + scol, Bs[NB] + w * 512); \
        glds16(W + (size_t)(bn + 64 + srow) * DMODEL + kt_ + scol, Bs[NB] + 2048 + w * 512); \
    } while (0)

    QKV_STAGE(0, 0);
    QKV_STAGE(1, 1);
    asm volatile("s_waitcnt vmcnt(4)" ::: "memory");   // tile 0 complete
    __builtin_amdgcn_s_barrier();

    int cur = 0, nx = 2;
    for (int i = 0; i < 32; i++) {
        bf16x8 af[4], bfr[4];
#pragma unroll
        for (int mi = 0; mi < 4; mi++)
            af[mi] = *(const bf16x8*)(As[cur] + (wr + mi * 16 + lm) * 32 + quad * 8);
#pragma unroll
        for (int ni = 0; ni < 4; ni++)
            bfr[ni] = *(const bf16x8*)(Bs[cur] + (wc + ni * 16 + lm) * 32 + quad * 8);
#pragma unroll
        for (int mi = 0; mi < 4; mi++)
#pragma unroll
            for (int ni = 0; ni < 4; ni++)
                acc[mi][ni] = __builtin_amdgcn_mfma_f32_16x16x32_bf16(
                    af[mi], bfr[ni], acc[mi][ni], 0, 0, 0);

        if (i + 2 < 32) {
            QKV_STAGE(i + 2, nx);
            asm volatile("s_waitcnt vmcnt(4)" ::: "memory");  // tile i+1 done
            __builtin_amdgcn_s_barrier();
        } else if (i + 1 < 32) {
            asm volatile("s_waitcnt vmcnt(0)" ::: "memory");
            __builtin_amdgcn_s_barrier();
        }
        cur = (cur == 2) ? 0 : cur + 1;
        nx  = (nx == 2) ? 0 : nx + 1;
    }
#undef QKV_STAGE

    const float sc = (z == 0) ? QSCALE : 1.0f;
    u16* outp = (z == 0) ? qo : (z == 1) ? ko : vto;
#pragma unroll
    for (int ni = 0; ni < 4; ni++) {
        int col = bn + wc + ni * 16 + lm;
        float bv = bias[col];
#pragma unroll
        for (int mi = 0; mi < 4; mi++)
            qkv_store(z, outp, bm + wr + mi * 16 + quad * 4, col, acc[mi][ni], bv, sc);
    }
}

// ---------------- legacy QKV (A f32 converted in staging; fallback paths) ----------------
template<bool WBF>
__global__ __launch_bounds__(256) void gemm_qkv(
    const float* __restrict__ Qf, const float* __restrict__ Kf, const float* __restrict__ Vf,
    const void* __restrict__ W0, const void* __restrict__ W1, const void* __restrict__ W2,
    const float* __restrict__ b0, const float* __restrict__ b1, const float* __restrict__ b2,
    u16* __restrict__ qo, u16* __restrict__ ko, u16* __restrict__ vto)
{
    __shared__ __align__(16) u16 As[128 * 32];
    __shared__ __align__(16) u16 Bs[128 * 32];
    const int tid = threadIdx.x, l = tid & 63, w = tid >> 6;
    const int lm = l & 15, quad = l >> 4;
    const int wr = (w >> 1) * 64, wc = (w & 1) * 64;
    const int bm = blockIdx.y * 128, bn = blockIdx.x * 128;
    const int z = blockIdx.z;
    const float* A    = (z == 0) ? Qf : (z == 1) ? Kf : Vf;
    const void* Wp    = (z == 0) ? W0 : (z == 1) ? W1 : W2;
    const float* bias = (z == 0) ? b0 : (z == 1) ? b1 : b2;

    floatx4 acc[4][4];
#pragma unroll
    for (int i = 0; i < 4; i++)
#pragma unroll
        for (int j = 0; j < 4; j++) acc[i][j] = (floatx4){0.f, 0.f, 0.f, 0.f};

    for (int kt = 0; kt < DMODEL; kt += 32) {
        __syncthreads();
#pragma unroll
        for (int j = 0; j < 2; j++) {
            int ch = j * 256 + tid, row = ch >> 2, c = ch & 3;
            *(uint4*)(As + ch * 8) = cvt8(A + (size_t)(bm + row) * DMODEL + kt + c * 8);
        }
        if (WBF) {
            const u16* Wb = (const u16*)Wp;
            glds16(Wb + (size_t)(bn + (tid >> 2)) * DMODEL + kt + (tid & 3) * 8, Bs + w * 512);
            glds16(Wb + (size_t)(bn + 64 + (tid >> 2)) * DMODEL + kt + (tid & 3) * 8, Bs + 2048 + w * 512);
        } else {
            const float* Wf = (const float*)Wp;
#pragma unroll
            for (int j = 0; j < 2; j++) {
                int ch = j * 256 + tid, row = ch >> 2, c = ch & 3;
                *(uint4*)(Bs + ch * 8) = cvt8(Wf + (size_t)(bn + row) * DMODEL + kt + c * 8);
            }
        }
        __syncthreads();

        bf16x8 af[4], bfr[4];
#pragma unroll
        for (int mi = 0; mi < 4; mi++)
            af[mi] = *(const bf16x8*)(As + (wr + mi * 16 + lm) * 32 + quad * 8);
#pragma unroll
        for (int ni = 0; ni < 4; ni++)
            bfr[ni] = *(const bf16x8*)(Bs + (wc + ni * 16 + lm) * 32 + quad * 8);
#pragma unroll
        for (int mi = 0; mi < 4; mi++)
#pragma unroll
            for (int ni = 0; ni < 4; ni++)
                acc[mi][ni] = __builtin_amdgcn_mfma_f32_16x16x32_bf16(
                    af[mi], bfr[ni], acc[mi][ni], 0, 0, 0);
    }

    const float sc = (z == 0) ? QSCALE : 1.0f;
    u16* outp = (z == 0) ? qo : (z == 1) ? ko : vto;
#pragma unroll
    for (int ni = 0; ni < 4; ni++) {
        int col = bn + wc + ni * 16 + lm;
        float bv = bias[col];
#pragma unroll
        for (int mi = 0; mi < 4; mi++)
            qkv_store(z, outp, bm + wr + mi * 16 + quad * 4, col, acc[mi][ni], bv, sc);
    }
}

// ---------------- O-projection v2 (bf16 W): 3-buffer pipeline like gemm_qkv_bb ----------------
__global__ __launch_bounds__(256) void gemm_o_p(
    const u16* __restrict__ A, const u16* __restrict__ W,
    const float* __restrict__ bias, float* __restrict__ out)
{
    __shared__ __align__(16) u16 As[3][4096];
    __shared__ __align__(16) u16 Bs[3][2048];
    const int tid = threadIdx.x, l = tid & 63, w = tid >> 6;
    const int lm = l & 15, quad = l >> 4;
    const int bm = blockIdx.y * 128, bn = blockIdx.x * 64;

    floatx4 acc[2][4];
#pragma unroll
    for (int i = 0; i < 2; i++)
#pragma unroll
        for (int j = 0; j < 4; j++) acc[i][j] = (floatx4){0.f, 0.f, 0.f, 0.f};

#define O_STAGE(I, NB) do { \
        const int kt_ = (I) * 32; \
        glds16(A + (size_t)(bm + (tid >> 2)) * DMODEL + kt_ + (tid & 3) * 8, As[NB] + w * 512); \
        glds16(A + (size_t)(bm + 64 + (tid >> 2)) * DMODEL + kt_ + (tid & 3) * 8, As[NB] + 2048 + w * 512); \
        glds16(W + (size_t)(bn + (tid >> 2)) * DMODEL + kt_ + (tid & 3) * 8, Bs[NB] + w * 512); \
    } while (0)

    O_STAGE(0, 0);
    O_STAGE(1, 1);
    asm volatile("s_waitcnt vmcnt(3)" ::: "memory");
    __builtin_amdgcn_s_barrier();

    int cur = 0, nx = 2;
    for (int i = 0; i < 32; i++) {
        bf16x8 af[2], bfr[4];
#pragma unroll
        for (int mi = 0; mi < 2; mi++)
            af[mi] = *(const bf16x8*)(As[cur] + (w * 32 + mi * 16 + lm) * 32 + quad * 8);
#pragma unroll
        for (int ni = 0; ni < 4; ni++)
            bfr[ni] = *(const bf16x8*)(Bs[cur] + (ni * 16 + lm) * 32 + quad * 8);
#pragma unroll
        for (int mi = 0; mi < 2; mi++)
#pragma unroll
            for (int ni = 0; ni < 4; ni++)
                acc[mi][ni] = __builtin_amdgcn_mfma_f32_16x16x32_bf16(
                    af[mi], bfr[ni], acc[mi][ni], 0, 0, 0);

        if (i + 2 < 32) {
            O_STAGE(i + 2, nx);
            asm volatile("s_waitcnt vmcnt(3)" ::: "memory");
            __builtin_amdgcn_s_barrier();
        } else if (i + 1 < 32) {
            asm volatile("s_waitcnt vmcnt(0)" ::: "memory");
            __builtin_amdgcn_s_barrier();
        }
        cur = (cur == 2) ? 0 : cur + 1;
        nx  = (nx == 2) ? 0 : nx + 1;
    }
#undef O_STAGE

#pragma unroll
    for (int ni = 0; ni < 4; ni++) {
        int col = bn + ni * 16 + lm;
        float bv = bias[col];
#pragma unroll
        for (int mi = 0; mi < 2; mi++) {
#pragma unroll
            for (int r = 0; r < 4; r++) {
                int rowg = bm + w * 32 + mi * 16 + quad * 4 + r;
                out[(size_t)rowg * DMODEL + col] = acc[mi][ni][r] + bv;
            }
        }
    }
}

// ---------------- legacy O-projection (f32 W fallback) ----------------
template<bool WBF>
__global__ __launch_bounds__(256) void gemm_o(
    const u16* __restrict__ A, const void* __restrict__ Wp,
    const float* __restrict__ bias, float* __restrict__ out)
{
    __shared__ __align__(16) u16 As[128 * 32];
    __shared__ __align__(16) u16 Bs[64 * 32];
    const int tid = threadIdx.x, l = tid & 63, w = tid >> 6;
    const int lm = l & 15, quad = l >> 4;
    const int bm = blockIdx.y * 128, bn = blockIdx.x * 64;

    floatx4 acc[2][4];
#pragma unroll
    for (int i = 0; i < 2; i++)
#pragma unroll
        for (int j = 0; j < 4; j++) acc[i][j] = (floatx4){0.f, 0.f, 0.f, 0.f};

    for (int kt = 0; kt < DMODEL; kt += 32) {
        __syncthreads();
        glds16(A + (size_t)(bm + (tid >> 2)) * DMODEL + kt + (tid & 3) * 8, As + w * 512);
        glds16(A + (size_t)(bm + 64 + (tid >> 2)) * DMODEL + kt + (tid & 3) * 8, As + 2048 + w * 512);
        if (WBF) {
            glds16((const u16*)Wp + (size_t)(bn + (tid >> 2)) * DMODEL + kt + (tid & 3) * 8, Bs + w * 512);
        } else {
            *(uint4*)(Bs + tid * 8) =
                cvt8((const float*)Wp + (size_t)(bn + (tid >> 2)) * DMODEL + kt + (tid & 3) * 8);
        }
        __syncthreads();

        bf16x8 af[2], bfr[4];
#pragma unroll
        for (int mi = 0; mi < 2; mi++)
            af[mi] = *(const bf16x8*)(As + (w * 32 + mi * 16 + lm) * 32 + quad * 8);
#pragma unroll
        for (int ni = 0; ni < 4; ni++)
            bfr[ni] = *(const bf16x8*)(Bs + (ni * 16 + lm) * 32 + quad * 8);
#pragma unroll
        for (int mi = 0; mi < 2; mi++)
#pragma unroll
            for (int ni = 0; ni < 4; ni++)
                acc[mi][ni] = __builtin_amdgcn_mfma_f32_16x16x32_bf16(
                    af[mi], bfr[ni], acc[mi][ni], 0, 0, 0);
    }

#pragma unroll
    for (int ni = 0; ni < 4; ni++) {
        int col = bn + ni * 16 + lm;
        float bv = bias[col];
#pragma unroll
        for (int mi = 0; mi < 2; mi++) {
#pragma unroll
            for (int r = 0; r < 4; r++) {
                int rowg = bm + w * 32 + mi * 16 + quad * 4 + r;
                out[(size_t)rowg * DMODEL + col] = acc[mi][ni][r] + bv;
            }
        }
    }
}

// ---------------- Flash attention v10: deferred-PV + raw barriers ----------------
// As v9 (KV-split, no-max softmax, double-buffer, l-via-ones-MFMA) plus:
//  (1) RAW s_barrier + lgkmcnt(0)-only: __syncthreads drains vmcnt(0) which
//      killed LOADT's latency hiding (loads issued right before the barrier).
//      Now vr prefetch loads stay in flight across barriers.
//  (2) Deferred PV (T15): iter t computes QK(t)->exp->pb_new, then PV(t-1)
//      with pb_old. PV is independent of the QK->exp serial chain, so the
//      scheduler overlays exp VALU under PV MFMA issue. pb double-buffered
//      via 2x-unrolled loop (static register indexing, rule #20).
//  Cost: 2 barriers/iter (PV(t-1) reads V buf (t-1)&1 which WRBUF(t+1) then
//  overwrites) - bar1 between them, bar2 after WRBUF for next QK.
#define SP 72
#define TS (64 * SP)          // one K or V tile in u16
#define BUFSZ (4 * TS)        // [K0][K1][V0][V1]

__device__ __forceinline__ void qk_exp_step(
    const u16* Kh, const bf16x8 (&qf)[2][2], int lm, int quad, bf16x4 (&pb)[4][2])
{
#pragma unroll
    for (int mt = 0; mt < 4; mt++) {
        bf16x8 ka0 = *(const bf16x8*)(Kh + (mt * 16 + lm) * SP + quad * 8);
        bf16x8 ka1 = *(const bf16x8*)(Kh + (mt * 16 + lm) * SP + 32 + quad * 8);
#pragma unroll
        for (int nt = 0; nt < 2; nt++) {
            floatx4 c = (floatx4){0.f, 0.f, 0.f, 0.f};
            c = __builtin_amdgcn_mfma_f32_16x16x32_bf16(ka0, qf[nt][0], c, 0, 0, 0);
            c = __builtin_amdgcn_mfma_f32_16x16x32_bf16(ka1, qf[nt][1], c, 0, 0, 0);
            union { u32 w2[2]; bf16x4 v; } pku;
            pku.w2[0] = pk2(ex2(c[0]), ex2(c[1]));
            pku.w2[1] = pk2(ex2(c[2]), ex2(c[3]));
            pb[mt][nt] = pku.v;
        }
    }
}

__device__ __forceinline__ void pv_step(
    const u16* Vh, const bf16x4 (&pb)[4][2], int lm, int quad,
    floatx4 (&O)[4][2], floatx4 (&Ol)[2], bf16x4 onesb)
{
#pragma unroll
    for (int nt = 0; nt < 2; nt++) {
        Ol[nt] = mfma16(onesb, pb[0][nt], Ol[nt]);
        Ol[nt] = mfma16(onesb, pb[1][nt], Ol[nt]);
        Ol[nt] = mfma16(onesb, pb[2][nt], Ol[nt]);
        Ol[nt] = mfma16(onesb, pb[3][nt], Ol[nt]);
    }
#pragma unroll
    for (int dt = 0; dt < 4; dt++) {
        const u16* vp = Vh + (dt * 16 + lm) * SP + quad * 16;
        bf16x8 v8a = *(const bf16x8*)vp;        // mt 0 (elems 0-3), mt 1 (4-7)
        bf16x8 v8b = *(const bf16x8*)(vp + 8);  // mt 2, mt 3
        bf16x4 va0 = __builtin_shufflevector(v8a, v8a, 0, 1, 2, 3);
        bf16x4 va1 = __builtin_shufflevector(v8a, v8a, 4, 5, 6, 7);
        bf16x4 va2 = __builtin_shufflevector(v8b, v8b, 0, 1, 2, 3);
        bf16x4 va3 = __builtin_shufflevector(v8b, v8b, 4, 5, 6, 7);
        O[dt][0] = mfma16(va0, pb[0][0], O[dt][0]);
        O[dt][1] = mfma16(va0, pb[0][1], O[dt][1]);
        O[dt][0] = mfma16(va1, pb[1][0], O[dt][0]);
        O[dt][1] = mfma16(va1, pb[1][1], O[dt][1]);
        O[dt][0] = mfma16(va2, pb[2][0], O[dt][0]);
        O[dt][1] = mfma16(va2, pb[2][1], O[dt][1]);
        O[dt][0] = mfma16(va3, pb[3][0], O[dt][0]);
        O[dt][1] = mfma16(va3, pb[3][1], O[dt][1]);
    }
}

__global__ __launch_bounds__(512, 4) void attn_kernel(
    const u16* __restrict__ q, const u16* __restrict__ k,
    const u16* __restrict__ vt, u16* __restrict__ out)
{
    __shared__ __align__(16) u16 smem[2 * BUFSZ];   // 73728 B
    const int tid = threadIdx.x, l = tid & 63, w = tid >> 6;   // w in 0..7
    const int lm = l & 15, quad = l >> 4;
    const int qt = blockIdx.x, bh = blockIdx.y;
    const int b = bh >> 4, h = bh & 15;
    const int rg = w & 3, half = w >> 2;

    bf16x8 qf[2][2];
#pragma unroll
    for (int nt = 0; nt < 2; nt++) {
        int row = qt * 128 + rg * 32 + nt * 16 + lm;
        const u16* qp = q + ((size_t)bh * SEQ + row) * DH;
        qf[nt][0] = *(const bf16x8*)(qp + quad * 8);
        qf[nt][1] = *(const bf16x8*)(qp + 32 + quad * 8);
    }

    floatx4 O[4][2];
#pragma unroll
    for (int dt = 0; dt < 4; dt++)
#pragma unroll
        for (int nt = 0; nt < 2; nt++) O[dt][nt] = (floatx4){0.f, 0.f, 0.f, 0.f};
    floatx4 Ol[2] = {(floatx4){0.f,0.f,0.f,0.f}, (floatx4){0.f,0.f,0.f,0.f}};
    bf16x4 pbA[4][2], pbB[4][2];

    const bf16x4 onesb = {(short)0x3F80, (short)0x3F80, (short)0x3F80, (short)0x3F80};

    const int srow = tid >> 3, scol = (tid & 7) * 8;  // srow 0..63, scol 0..56
    const int pb0 = ((scol >> 2) & 3) * 16 + (scol >> 4) * 4;
    const u16* kbase = k + (size_t)bh * SEQ * DH;
    const u16* vbase = vt + (size_t)bh * DH * SEQ;

    uint4 krA, krB, vrA, vrB;
#define LOADT(T) do { \
        const u16* kg = kbase + (size_t)(T) * 64 * DH; \
        const u16* vg = vbase + (size_t)(T) * 64; \
        krA = *(const uint4*)(kg + (size_t)srow * DH + scol); \
        krB = *(const uint4*)(kg + (size_t)(1024 + srow) * DH + scol); \
        vrA = *(const uint4*)(vg + (size_t)srow * SEQ + scol); \
        vrB = *(const uint4*)(vg + (size_t)srow * SEQ + 1024 + scol); \
    } while (0)
#define WRBUF(BUF) do { \
        u16* K0 = smem + (BUF) * BUFSZ; \
        u16* K1 = K0 + TS; \
        u16* V0 = K0 + 2 * TS; \
        u16* V1 = K0 + 3 * TS; \
        *(uint4*)(K0 + srow * SP + scol) = krA; \
        *(uint4*)(K1 + srow * SP + scol) = krB; \
        *(uint2*)(V0 + srow * SP + pb0)      = make_uint2(vrA.x, vrA.y); \
        *(uint2*)(V0 + srow * SP + pb0 + 16) = make_uint2(vrA.z, vrA.w); \
        *(uint2*)(V1 + srow * SP + pb0)      = make_uint2(vrB.x, vrB.y); \
        *(uint2*)(V1 + srow * SP + pb0 + 16) = make_uint2(vrB.z, vrB.w); \
    } while (0)

    LOADT(0);
    WRBUF(0);
    LOADT(1);
    __syncthreads();

    // t = 0: QK+exp only (no PV(-1)); WRBUF(1) touches buf1 which nobody reads
    __builtin_amdgcn_s_setprio(1);
    qk_exp_step(smem + half * TS, qf, lm, quad, pbA);
    __builtin_amdgcn_s_setprio(0);
    WRBUF(1);
    LOADT(2);
    asm volatile("s_waitcnt lgkmcnt(0)" ::: "memory");
    __builtin_amdgcn_s_barrier();

#define AITER(T, PBOLD, PBNEW) do { \
        const u16* Kh_ = smem + ((T) & 1) * BUFSZ + half * TS; \
        const u16* Vh_ = smem + (((T) - 1) & 1) * BUFSZ + (2 + half) * TS; \
        __builtin_amdgcn_s_setprio(1); \
        qk_exp_step(Kh_, qf, lm, quad, PBNEW); \
        pv_step(Vh_, PBOLD, lm, quad, O, Ol, onesb); \
        __builtin_amdgcn_s_setprio(0); \
        __builtin_amdgcn_s_barrier(); \
        WRBUF(((T) + 1) & 1); \
        if ((T) + 2 < 16) LOADT((T) + 2); \
        asm volatile("s_waitcnt lgkmcnt(0)" ::: "memory"); \
        __builtin_amdgcn_s_barrier(); \
    } while (0)

    for (int td = 0; td < 7; td++) {
        AITER(2 * td + 1, pbA, pbB);
        AITER(2 * td + 2, pbB, pbA);
    }
    // t = 15 tail: QK(15)->pbB, then PV(14) with pbA and PV(15) with pbB
    __builtin_amdgcn_s_setprio(1);
    qk_exp_step(smem + BUFSZ + half * TS, qf, lm, quad, pbB);
    pv_step(smem + (2 + half) * TS, pbA, lm, quad, O, Ol, onesb);           // buf0 V
    pv_step(smem + BUFSZ + (2 + half) * TS, pbB, lm, quad, O, Ol, onesb);   // buf1 V
    __builtin_amdgcn_s_setprio(0);
#undef AITER
#undef LOADT
#undef WRBUF

    __syncthreads();
    // ---- in-block merge of the two key-halves through LDS (f32) ----
    // no-max: O = (O_A + O_B) / (l_A + l_B)
    float* obuf  = (float*)smem;           // [4 rg][64 lane][2 nt][16] = 32768B
    float* mlbuf = (float*)smem + 8192;    // [4 rg][64 lane][2 nt]     =  2048B
    if (w >= 4) {
#pragma unroll
        for (int nt = 0; nt < 2; nt++) {
            float* ob = obuf + (((rg * 64 + l) * 2 + nt) << 4);
#pragma unroll
            for (int dt = 0; dt < 4; dt++)
                *(floatx4*)(ob + dt * 4) = O[dt][nt];
            mlbuf[(rg * 64 + l) * 2 + nt] = Ol[nt][0];
        }
    }
    __syncthreads();
    if (w < 4) {
#pragma unroll
        for (int nt = 0; nt < 2; nt++) {
            float* ob = obuf + (((rg * 64 + l) * 2 + nt) << 4);
            float lB = mlbuf[(rg * 64 + l) * 2 + nt];
            float inv = 1.0f / (Ol[nt][0] + lB);
            int s = qt * 128 + rg * 32 + nt * 16 + lm;
            u16* op = out + ((size_t)b * SEQ + s) * DMODEL + h * DH;
#pragma unroll
            for (int dt = 0; dt < 4; dt++) {
                floatx4 Ob = *(const floatx4*)(ob + dt * 4);
                union { u32 w2[2]; u16x4 v; } pku;
                pku.w2[0] = pk2((O[dt][nt][0] + Ob[0]) * inv,
                                (O[dt][nt][1] + Ob[1]) * inv);
                pku.w2[1] = pk2((O[dt][nt][2] + Ob[2]) * inv,
                                (O[dt][nt][3] + Ob[3]) * inv);
                *(u16x4*)(op + dt * 16 + quad * 4) = pku.v;
            }
        }
    }
}

extern "C" void kernel_launch(void* const* d_in, const int* in_sizes, int n_in,
                              void* d_out, int out_size, void* d_ws, size_t ws_size,
                              hipStream_t stream) {
    (void)in_sizes; (void)n_in; (void)out_size;
    const float* Q  = (const float*)d_in[0];
    const float* K  = (const float*)d_in[1];
    const float* V  = (const float*)d_in[2];
    const float* Wq = (const float*)d_in[3];
    const float* bq = (const float*)d_in[4];
    const float* Wk = (const float*)d_in[5];
    const float* bk = (const float*)d_in[6];
    const float* Wv = (const float*)d_in[7];
    const float* bv = (const float*)d_in[8];
    const float* Wo = (const float*)d_in[9];
    const float* bo = (const float*)d_in[10];

    const size_t NEL = (size_t)2 * NH * SEQ * DH;  // 4,194,304 elements
    u16* base = (u16*)d_ws;
    dim3 bb(256);
    dim3 ab(512);

    if (ws_size >= 8 * NEL * 2) {
        u16* Qb   = base;
        u16* Kb   = Qb + NEL;
        u16* Vb   = Kb + NEL;
        u16* Wb   = Vb + NEL;
        u16* qws  = Wb + NEL;
        u16* kws  = qws + NEL;
        u16* vtws = kws + NEL;
        u16* aws  = vtws + NEL;
        cvt_all<<<dim3(2048, 7), bb, 0, stream>>>(Q, K, V, Wq, Wk, Wv, Wo, Qb, Kb, Vb, Wb);
        gemm_qkv_bb<<<dim3(8, 32, 3), bb, 0, stream>>>(
            Qb, Kb, Vb, Wb, bq, bk, bv, qws, kws, vtws);
        attn_kernel<<<dim3(SEQ / 128, 2 * NH), ab, 0, stream>>>(qws, kws, vtws, aws);
        gemm_o_p<<<dim3(16, 32), bb, 0, stream>>>(aws, Wb + 3145728, bo, (float*)d_out);
    } else if (ws_size >= 5 * NEL * 2) {
        u16* Wb = base;
        u16* qws = base + NEL; u16* kws = qws + NEL; u16* vtws = kws + NEL; u16* aws = vtws + NEL;
        cvt_w<<<dim3(512, 4), bb, 0, stream>>>(Wq, Wk, Wv, Wo, Wb);
        gemm_qkv<true><<<dim3(8, 32, 3), bb, 0, stream>>>(
            Q, K, V, Wb, Wb + 1048576, Wb + 2097152, bq, bk, bv, qws, kws, vtws);
        attn_kernel<<<dim3(SEQ / 128, 2 * NH), ab, 0, stream>>>(qws, kws, vtws, aws);
        gemm_o_p<<<dim3(16, 32), bb, 0, stream>>>(aws, Wb + 3145728, bo, (float*)d_out);
    } else {
        u16* qws = base; u16* kws = qws + NEL; u16* vtws = kws + NEL; u16* aws = vtws + NEL;
        gemm_qkv<false><<<dim3(8, 32, 3), bb, 0, stream>>>(
            Q, K, V, Wq, Wk, Wv, bq, bk, bv, qws, kws, vtws);
        attn_kernel<<<dim3(SEQ / 128, 2 * NH), ab, 0, stream>>>(qws, kws, vtws, aws);
        gemm_o<false><<<dim3(16, 32), bb, 0, stream>>>(aws, Wo, bo, (float*)d_out);
    }
}

// Round 6
// 227.594 us; speedup vs baseline: 1.2275x; 1.2275x over previous
//
#include <hip/hip_runtime.h>

#define SEQ 2048
#define DMODEL 1024
#define NH 16
#define DH 64

typedef __attribute__((ext_vector_type(8))) short bf16x8;
typedef __attribute__((ext_vector_type(4))) short bf16x4;
typedef __attribute__((ext_vector_type(4))) float floatx4;
typedef __attribute__((ext_vector_type(4))) unsigned short u16x4;
typedef unsigned short u16;
typedef unsigned int u32;

typedef const void __attribute__((address_space(1)))* as1cvp;
typedef void __attribute__((address_space(3)))* as3vp;

__device__ __forceinline__ void glds16(const void* g, void* l) {
    __builtin_amdgcn_global_load_lds((as1cvp)g, (as3vp)l, 16, 0, 0);
}

// f32->bf16 round-half-up: u + 0x8000, take hi16. Same 0.5-ulp worst case as
// RNE (only exact-tie direction differs -> unbiased for continuous data).
__device__ __forceinline__ u16 f2bf(float f) {
    union { u32 u; float f; } v; v.f = f;
    return (u16)((v.u + 0x8000u) >> 16);
}

// packed f32->2xbf16 half-up: 2 adds + 1 v_perm_b32 (hi16 of each)
__device__ __forceinline__ u32 pk2(float a, float b) {
    union { u32 u; float f; } x, y; x.f = a; y.f = b;
    u32 xr = x.u + 0x8000u, yr = y.u + 0x8000u;
#if __has_builtin(__builtin_amdgcn_perm)
    return __builtin_amdgcn_perm(yr, xr, 0x07060302u);
#else
    return (xr >> 16) | (yr & 0xffff0000u);
#endif
}

// raw v_exp_f32 (= exp2); log2e folded into QSCALE so scores are log2-domain.
__device__ __forceinline__ float ex2(float x) {
#if __has_builtin(__builtin_amdgcn_exp2f)
    return __builtin_amdgcn_exp2f(x);
#else
    float r; asm("v_exp_f32 %0, %1" : "=v"(r) : "v"(x)); return r;
#endif
}

// 16x16x16 bf16 MFMA: B-frag layout k=quad*4+j matches C-layout of S^T
__device__ __forceinline__ floatx4 mfma16(bf16x4 a, bf16x4 b, floatx4 c) {
#if __has_builtin(__builtin_amdgcn_mfma_f32_16x16x16bf16_1k)
    return __builtin_amdgcn_mfma_f32_16x16x16bf16_1k(a, b, c, 0, 0, 0);
#else
    asm volatile("v_mfma_f32_16x16x16_bf16 %0, %1, %2, %0" : "+v"(c) : "v"(a), "v"(b));
    return c;
#endif
}

__device__ __forceinline__ uint4 cvt8(const float* __restrict__ p) {
    float4 a = *(const float4*)p;
    float4 b = *(const float4*)(p + 4);
    uint4 q;
    q.x = pk2(a.x, a.y); q.y = pk2(a.z, a.w);
    q.z = pk2(b.x, b.y); q.w = pk2(b.z, b.w);
    return q;
}

// q pre-scale: 1/sqrt(Dh) * log2(e) -> scores are log2-domain, exp via v_exp_f32
#define QSCALE 0.18033688011112042f

// ---------------- convert Q,K,V + 4 weights to bf16 once ----------------
__global__ __launch_bounds__(256) void cvt_all(
    const float* __restrict__ Q, const float* __restrict__ K, const float* __restrict__ V,
    const float* __restrict__ W0, const float* __restrict__ W1,
    const float* __restrict__ W2, const float* __restrict__ W3,
    u16* __restrict__ Qb, u16* __restrict__ Kb, u16* __restrict__ Vb,
    u16* __restrict__ Wb)
{
    const int y = blockIdx.y;
    const float* src; u16* dst;
    if (y == 0)      { src = Q;  dst = Qb; }
    else if (y == 1) { src = K;  dst = Kb; }
    else if (y == 2) { src = V;  dst = Vb; }
    else {
        if (blockIdx.x >= 512) return;
        src = (y == 3) ? W0 : (y == 4) ? W1 : (y == 5) ? W2 : W3;
        dst = Wb + (size_t)(y - 3) * 1048576;
    }
    size_t i = ((size_t)blockIdx.x * 256 + threadIdx.x) * 8;
    *(uint4*)(dst + i) = cvt8(src + i);
}

__global__ __launch_bounds__(256) void cvt_w(
    const float* __restrict__ W0, const float* __restrict__ W1,
    const float* __restrict__ W2, const float* __restrict__ W3,
    u16* __restrict__ out)
{
    const float* src = (blockIdx.y == 0) ? W0 : (blockIdx.y == 1) ? W1
                     : (blockIdx.y == 2) ? W2 : W3;
    size_t i = ((size_t)blockIdx.x * 256 + threadIdx.x) * 8;
    *(uint4*)(out + (size_t)blockIdx.y * 1048576 + i) = cvt8(src + i);
}

// shared epilogue store for QKV projections (z<2: scalar, z=2: vectorized 8B)
__device__ __forceinline__ void qkv_store(
    int z, u16* __restrict__ outp, int rowg, int col, floatx4 a4, float bv, float sc)
{
    union { u32 w[2]; u16 h[4]; u16x4 v4; } pk;
    pk.w[0] = pk2((a4[0] + bv) * sc, (a4[1] + bv) * sc);
    pk.w[1] = pk2((a4[2] + bv) * sc, (a4[3] + bv) * sc);
    int b = rowg >> 11, s = rowg & 2047, h = col >> 6, d = col & 63;
    if (z < 2) {
#pragma unroll
        for (int r = 0; r < 4; r++)
            outp[((size_t)(b * NH + h) * SEQ + s + r) * DH + d] = pk.h[r];
    } else {
        *(u16x4*)(outp + ((size_t)(b * NH + h) * DH + d) * SEQ + s) = pk.v4;
    }
}

// ---------------- QKV projection: 3-buffer LDS pipeline, counted vmcnt ----------------
// NB=3 ring: stage(i+2), vmcnt(4) [tile i+1 done, i+2 in flight], RAW s_barrier
// (no implicit drain), compute(i). Writer buf (i+2)%3 never collides with
// concurrent readers' (i)%3 / (i+1)%3 -> single barrier per step is safe.
__global__ __launch_bounds__(256) void gemm_qkv_bb(
    const u16* __restrict__ Qb, const u16* __restrict__ Kb, const u16* __restrict__ Vb,
    const u16* __restrict__ Wb,
    const float* __restrict__ b0, const float* __restrict__ b1, const float* __restrict__ b2,
    u16* __restrict__ qo, u16* __restrict__ ko, u16* __restrict__ vto)
{
    __shared__ __align__(16) u16 As[3][4096];
    __shared__ __align__(16) u16 Bs[3][4096];
    const int tid = threadIdx.x, l = tid & 63, w = tid >> 6;
    const int lm = l & 15, quad = l >> 4;
    const int wr = (w >> 1) * 64, wc = (w & 1) * 64;
    const int bm = blockIdx.y * 128, bn = blockIdx.x * 128;
    const int z = blockIdx.z;
    const u16* A      = (z == 0) ? Qb : (z == 1) ? Kb : Vb;
    const u16* W      = Wb + (size_t)z * 1048576;
    const float* bias = (z == 0) ? b0 : (z == 1) ? b1 : b2;

    const int srow = tid >> 2, scol = (tid & 3) * 8;

    floatx4 acc[4][4];
#pragma unroll
    for (int i = 0; i < 4; i++)
#pragma unroll
        for (int j = 0; j < 4; j++) acc[i][j] = (floatx4){0.f, 0.f, 0.f, 0.f};

#define QKV_STAGE(I, NB) do { \
        const int kt_ = (I) * 32; \
        glds16(A + (size_t)(bm + srow) * DMODEL + kt_ + scol, As[NB] + w * 512); \
        glds16(A + (size_t)(bm + 64 + srow) * DMODEL + kt_ + scol, As[NB] + 2048 + w * 512); \
        glds16(W + (size_t)(bn + srow) * DMODEL + kt_ + scol, Bs[NB] + w * 512); \
        glds16(W + (size_t)(bn + 64 + srow) * DMODEL + kt_ + scol, Bs[NB] + 2048 + w * 512); \
    } while (0)

    QKV_STAGE(0, 0);
    QKV_STAGE(1, 1);
    asm volatile("s_waitcnt vmcnt(4)" ::: "memory");   // tile 0 complete
    __builtin_amdgcn_s_barrier();

    int cur = 0, nx = 2;
    for (int i = 0; i < 32; i++) {
        bf16x8 af[4], bfr[4];
#pragma unroll
        for (int mi = 0; mi < 4; mi++)
            af[mi] = *(const bf16x8*)(As[cur] + (wr + mi * 16 + lm) * 32 + quad * 8);
#pragma unroll
        for (int ni = 0; ni < 4; ni++)
            bfr[ni] = *(const bf16x8*)(Bs[cur] + (wc + ni * 16 + lm) * 32 + quad * 8);
#pragma unroll
        for (int mi = 0; mi < 4; mi++)
#pragma unroll
            for (int ni = 0; ni < 4; ni++)
                acc[mi][ni] = __builtin_amdgcn_mfma_f32_16x16x32_bf16(
                    af[mi], bfr[ni], acc[mi][ni], 0, 0, 0);

        if (i + 2 < 32) {
            QKV_STAGE(i + 2, nx);
            asm volatile("s_waitcnt vmcnt(4)" ::: "memory");  // tile i+1 done
            __builtin_amdgcn_s_barrier();
        } else if (i + 1 < 32) {
            asm volatile("s_waitcnt vmcnt(0)" ::: "memory");
            __builtin_amdgcn_s_barrier();
        }
        cur = (cur == 2) ? 0 : cur + 1;
        nx  = (nx == 2) ? 0 : nx + 1;
    }
#undef QKV_STAGE

    const float sc = (z == 0) ? QSCALE : 1.0f;
    u16* outp = (z == 0) ? qo : (z == 1) ? ko : vto;
#pragma unroll
    for (int ni = 0; ni < 4; ni++) {
        int col = bn + wc + ni * 16 + lm;
        float bv = bias[col];
#pragma unroll
        for (int mi = 0; mi < 4; mi++)
            qkv_store(z, outp, bm + wr + mi * 16 + quad * 4, col, acc[mi][ni], bv, sc);
    }
}

// ---------------- legacy QKV (A f32 converted in staging; fallback paths) ----------------
template<bool WBF>
__global__ __launch_bounds__(256) void gemm_qkv(
    const float* __restrict__ Qf, const float* __restrict__ Kf, const float* __restrict__ Vf,
    const void* __restrict__ W0, const void* __restrict__ W1, const void* __restrict__ W2,
    const float* __restrict__ b0, const float* __restrict__ b1, const float* __restrict__ b2,
    u16* __restrict__ qo, u16* __restrict__ ko, u16* __restrict__ vto)
{
    __shared__ __align__(16) u16 As[128 * 32];
    __shared__ __align__(16) u16 Bs[128 * 32];
    const int tid = threadIdx.x, l = tid & 63, w = tid >> 6;
    const int lm = l & 15, quad = l >> 4;
    const int wr = (w >> 1) * 64, wc = (w & 1) * 64;
    const int bm = blockIdx.y * 128, bn = blockIdx.x * 128;
    const int z = blockIdx.z;
    const float* A    = (z == 0) ? Qf : (z == 1) ? Kf : Vf;
    const void* Wp    = (z == 0) ? W0 : (z == 1) ? W1 : W2;
    const float* bias = (z == 0) ? b0 : (z == 1) ? b1 : b2;

    floatx4 acc[4][4];
#pragma unroll
    for (int i = 0; i < 4; i++)
#pragma unroll
        for (int j = 0; j < 4; j++) acc[i][j] = (floatx4){0.f, 0.f, 0.f, 0.f};

    for (int kt = 0; kt < DMODEL; kt += 32) {
        __syncthreads();
#pragma unroll
        for (int j = 0; j < 2; j++) {
            int ch = j * 256 + tid, row = ch >> 2, c = ch & 3;
            *(uint4*)(As + ch * 8) = cvt8(A + (size_t)(bm + row) * DMODEL + kt + c * 8);
        }
        if (WBF) {
            const u16* Wb = (const u16*)Wp;
            glds16(Wb + (size_t)(bn + (tid >> 2)) * DMODEL + kt + (tid & 3) * 8, Bs + w * 512);
            glds16(Wb + (size_t)(bn + 64 + (tid >> 2)) * DMODEL + kt + (tid & 3) * 8, Bs + 2048 + w * 512);
        } else {
            const float* Wf = (const float*)Wp;
#pragma unroll
            for (int j = 0; j < 2; j++) {
                int ch = j * 256 + tid, row = ch >> 2, c = ch & 3;
                *(uint4*)(Bs + ch * 8) = cvt8(Wf + (size_t)(bn + row) * DMODEL + kt + c * 8);
            }
        }
        __syncthreads();

        bf16x8 af[4], bfr[4];
#pragma unroll
        for (int mi = 0; mi < 4; mi++)
            af[mi] = *(const bf16x8*)(As + (wr + mi * 16 + lm) * 32 + quad * 8);
#pragma unroll
        for (int ni = 0; ni < 4; ni++)
            bfr[ni] = *(const bf16x8*)(Bs + (wc + ni * 16 + lm) * 32 + quad * 8);
#pragma unroll
        for (int mi = 0; mi < 4; mi++)
#pragma unroll
            for (int ni = 0; ni < 4; ni++)
                acc[mi][ni] = __builtin_amdgcn_mfma_f32_16x16x32_bf16(
                    af[mi], bfr[ni], acc[mi][ni], 0, 0, 0);
    }

    const float sc = (z == 0) ? QSCALE : 1.0f;
    u16* outp = (z == 0) ? qo : (z == 1) ? ko : vto;
#pragma unroll
    for (int ni = 0; ni < 4; ni++) {
        int col = bn + wc + ni * 16 + lm;
        float bv = bias[col];
#pragma unroll
        for (int mi = 0; mi < 4; mi++)
            qkv_store(z, outp, bm + wr + mi * 16 + quad * 4, col, acc[mi][ni], bv, sc);
    }
}

// ---------------- O-projection (bf16 W): 3-buffer pipeline like gemm_qkv_bb ----------------
__global__ __launch_bounds__(256) void gemm_o_p(
    const u16* __restrict__ A, const u16* __restrict__ W,
    const float* __restrict__ bias, float* __restrict__ out)
{
    __shared__ __align__(16) u16 As[3][4096];
    __shared__ __align__(16) u16 Bs[3][2048];
    const int tid = threadIdx.x, l = tid & 63, w = tid >> 6;
    const int lm = l & 15, quad = l >> 4;
    const int bm = blockIdx.y * 128, bn = blockIdx.x * 64;

    floatx4 acc[2][4];
#pragma unroll
    for (int i = 0; i < 2; i++)
#pragma unroll
        for (int j = 0; j < 4; j++) acc[i][j] = (floatx4){0.f, 0.f, 0.f, 0.f};

#define O_STAGE(I, NB) do { \
        const int kt_ = (I) * 32; \
        glds16(A + (size_t)(bm + (tid >> 2)) * DMODEL + kt_ + (tid & 3) * 8, As[NB] + w * 512); \
        glds16(A + (size_t)(bm + 64 + (tid >> 2)) * DMODEL + kt_ + (tid & 3) * 8, As[NB] + 2048 + w * 512); \
        glds16(W + (size_t)(bn + (tid >> 2)) * DMODEL + kt_ + (tid & 3) * 8, Bs[NB] + w * 512); \
    } while (0)

    O_STAGE(0, 0);
    O_STAGE(1, 1);
    asm volatile("s_waitcnt vmcnt(3)" ::: "memory");
    __builtin_amdgcn_s_barrier();

    int cur = 0, nx = 2;
    for (int i = 0; i < 32; i++) {
        bf16x8 af[2], bfr[4];
#pragma unroll
        for (int mi = 0; mi < 2; mi++)
            af[mi] = *(const bf16x8*)(As[cur] + (w * 32 + mi * 16 + lm) * 32 + quad * 8);
#pragma unroll
        for (int ni = 0; ni < 4; ni++)
            bfr[ni] = *(const bf16x8*)(Bs[cur] + (ni * 16 + lm) * 32 + quad * 8);
#pragma unroll
        for (int mi = 0; mi < 2; mi++)
#pragma unroll
            for (int ni = 0; ni < 4; ni++)
                acc[mi][ni] = __builtin_amdgcn_mfma_f32_16x16x32_bf16(
                    af[mi], bfr[ni], acc[mi][ni], 0, 0, 0);

        if (i + 2 < 32) {
            O_STAGE(i + 2, nx);
            asm volatile("s_waitcnt vmcnt(3)" ::: "memory");
            __builtin_amdgcn_s_barrier();
        } else if (i + 1 < 32) {
            asm volatile("s_waitcnt vmcnt(0)" ::: "memory");
            __builtin_amdgcn_s_barrier();
        }
        cur = (cur == 2) ? 0 : cur + 1;
        nx  = (nx == 2) ? 0 : nx + 1;
    }
#undef O_STAGE

#pragma unroll
    for (int ni = 0; ni < 4; ni++) {
        int col = bn + ni * 16 + lm;
        float bv = bias[col];
#pragma unroll
        for (int mi = 0; mi < 2; mi++) {
#pragma unroll
            for (int r = 0; r < 4; r++) {
                int rowg = bm + w * 32 + mi * 16 + quad * 4 + r;
                out[(size_t)rowg * DMODEL + col] = acc[mi][ni][r] + bv;
            }
        }
    }
}

// ---------------- legacy O-projection (f32 W fallback) ----------------
template<bool WBF>
__global__ __launch_bounds__(256) void gemm_o(
    const u16* __restrict__ A, const void* __restrict__ Wp,
    const float* __restrict__ bias, float* __restrict__ out)
{
    __shared__ __align__(16) u16 As[128 * 32];
    __shared__ __align__(16) u16 Bs[64 * 32];
    const int tid = threadIdx.x, l = tid & 63, w = tid >> 6;
    const int lm = l & 15, quad = l >> 4;
    const int bm = blockIdx.y * 128, bn = blockIdx.x * 64;

    floatx4 acc[2][4];
#pragma unroll
    for (int i = 0; i < 2; i++)
#pragma unroll
        for (int j = 0; j < 4; j++) acc[i][j] = (floatx4){0.f, 0.f, 0.f, 0.f};

    for (int kt = 0; kt < DMODEL; kt += 32) {
        __syncthreads();
        glds16(A + (size_t)(bm + (tid >> 2)) * DMODEL + kt + (tid & 3) * 8, As + w * 512);
        glds16(A + (size_t)(bm + 64 + (tid >> 2)) * DMODEL + kt + (tid & 3) * 8, As + 2048 + w * 512);
        if (WBF) {
            glds16((const u16*)Wp + (size_t)(bn + (tid >> 2)) * DMODEL + kt + (tid & 3) * 8, Bs + w * 512);
        } else {
            *(uint4*)(Bs + tid * 8) =
                cvt8((const float*)Wp + (size_t)(bn + (tid >> 2)) * DMODEL + kt + (tid & 3) * 8);
        }
        __syncthreads();

        bf16x8 af[2], bfr[4];
#pragma unroll
        for (int mi = 0; mi < 2; mi++)
            af[mi] = *(const bf16x8*)(As + (w * 32 + mi * 16 + lm) * 32 + quad * 8);
#pragma unroll
        for (int ni = 0; ni < 4; ni++)
            bfr[ni] = *(const bf16x8*)(Bs + (ni * 16 + lm) * 32 + quad * 8);
#pragma unroll
        for (int mi = 0; mi < 2; mi++)
#pragma unroll
            for (int ni = 0; ni < 4; ni++)
                acc[mi][ni] = __builtin_amdgcn_mfma_f32_16x16x32_bf16(
                    af[mi], bfr[ni], acc[mi][ni], 0, 0, 0);
    }

#pragma unroll
    for (int ni = 0; ni < 4; ni++) {
        int col = bn + ni * 16 + lm;
        float bv = bias[col];
#pragma unroll
        for (int mi = 0; mi < 2; mi++) {
#pragma unroll
            for (int r = 0; r < 4; r++) {
                int rowg = bm + w * 32 + mi * 16 + quad * 4 + r;
                out[(size_t)rowg * DMODEL + col] = acc[mi][ni][r] + bv;
            }
        }
    }
}

// ---------------- Flash attention v9R: v9 + raw barriers (no vmcnt drain) ----------------
// Exactly v9's structure/register budget (64 VGPR, no spill -- v10's deferred-PV
// spilled 380MB/dispatch to scratch, r5 post-mortem). Change vs v9: the loop
// barrier is lgkmcnt(0) + RAW s_barrier. Explicit vmcnt(0) BEFORE WRBUF drains
// only the tile-(t+1) loads (issued one full compute phase ago -> already
// landed); LOADT(t+2) issues AFTER and stays in flight across the barrier,
// hiding HBM latency under the next tile's compute. Race-free: compute(t)
// reads buf t&1, WRBUF writes buf (t+1)&1, one barrier separates iterations.
#define SP 72
#define TS (64 * SP)          // one K or V tile in u16
#define BUFSZ (4 * TS)        // [K0][K1][V0][V1]
__global__ __launch_bounds__(512, 4) void attn_kernel(
    const u16* __restrict__ q, const u16* __restrict__ k,
    const u16* __restrict__ vt, u16* __restrict__ out)
{
    __shared__ __align__(16) u16 smem[2 * BUFSZ];   // 73728 B
    const int tid = threadIdx.x, l = tid & 63, w = tid >> 6;   // w in 0..7
    const int lm = l & 15, quad = l >> 4;
    const int qt = blockIdx.x, bh = blockIdx.y;
    const int b = bh >> 4, h = bh & 15;
    const int rg = w & 3, half = w >> 2;

    bf16x8 qf[2][2];
#pragma unroll
    for (int nt = 0; nt < 2; nt++) {
        int row = qt * 128 + rg * 32 + nt * 16 + lm;
        const u16* qp = q + ((size_t)bh * SEQ + row) * DH;
        qf[nt][0] = *(const bf16x8*)(qp + quad * 8);
        qf[nt][1] = *(const bf16x8*)(qp + 32 + quad * 8);
    }

    floatx4 O[4][2];
#pragma unroll
    for (int dt = 0; dt < 4; dt++)
#pragma unroll
        for (int nt = 0; nt < 2; nt++) O[dt][nt] = (floatx4){0.f, 0.f, 0.f, 0.f};
    floatx4 Ol[2] = {(floatx4){0.f,0.f,0.f,0.f}, (floatx4){0.f,0.f,0.f,0.f}};

    const bf16x4 onesb = {(short)0x3F80, (short)0x3F80, (short)0x3F80, (short)0x3F80};

    const int srow = tid >> 3, scol = (tid & 7) * 8;  // srow 0..63, scol 0..56
    // permuted V position base: chunk scol..scol+3 -> pb0, scol+4..scol+7 -> pb0+16
    const int pb0 = ((scol >> 2) & 3) * 16 + (scol >> 4) * 4;
    const u16* kbase = k + (size_t)bh * SEQ * DH;
    const u16* vbase = vt + (size_t)bh * DH * SEQ;

    uint4 krA, krB, vrA, vrB;
#define LOADT(T) do { \
        const u16* kg = kbase + (size_t)(T) * 64 * DH; \
        const u16* vg = vbase + (size_t)(T) * 64; \
        krA = *(const uint4*)(kg + (size_t)srow * DH + scol); \
        krB = *(const uint4*)(kg + (size_t)(1024 + srow) * DH + scol); \
        vrA = *(const uint4*)(vg + (size_t)srow * SEQ + scol); \
        vrB = *(const uint4*)(vg + (size_t)srow * SEQ + 1024 + scol); \
    } while (0)
#define WRBUF(BUF) do { \
        u16* K0 = smem + (BUF) * BUFSZ; \
        u16* K1 = K0 + TS; \
        u16* V0 = K0 + 2 * TS; \
        u16* V1 = K0 + 3 * TS; \
        *(uint4*)(K0 + srow * SP + scol) = krA; \
        *(uint4*)(K1 + srow * SP + scol) = krB; \
        *(uint2*)(V0 + srow * SP + pb0)      = make_uint2(vrA.x, vrA.y); \
        *(uint2*)(V0 + srow * SP + pb0 + 16) = make_uint2(vrA.z, vrA.w); \
        *(uint2*)(V1 + srow * SP + pb0)      = make_uint2(vrB.x, vrB.y); \
        *(uint2*)(V1 + srow * SP + pb0 + 16) = make_uint2(vrB.z, vrB.w); \
    } while (0)

    LOADT(0);
    WRBUF(0);
    LOADT(1);
    asm volatile("s_waitcnt lgkmcnt(0)" ::: "memory");
    __builtin_amdgcn_s_barrier();

    for (int t = 0; t < 16; t++) {
        const int cur = t & 1;
        const u16* Kh = smem + cur * BUFSZ + half * TS;
        const u16* Vh = smem + cur * BUFSZ + (2 + half) * TS;

        // S^T = K·Q^T (K-frag reads shared across both n-tiles)
        floatx4 Sc[4][2];
        __builtin_amdgcn_s_setprio(1);
#pragma unroll
        for (int mt = 0; mt < 4; mt++) {
            bf16x8 ka0 = *(const bf16x8*)(Kh + (mt * 16 + lm) * SP + quad * 8);
            bf16x8 ka1 = *(const bf16x8*)(Kh + (mt * 16 + lm) * SP + 32 + quad * 8);
#pragma unroll
            for (int nt = 0; nt < 2; nt++) {
                floatx4 c = (floatx4){0.f, 0.f, 0.f, 0.f};
                c = __builtin_amdgcn_mfma_f32_16x16x32_bf16(ka0, qf[nt][0], c, 0, 0, 0);
                c = __builtin_amdgcn_mfma_f32_16x16x32_bf16(ka1, qf[nt][1], c, 0, 0, 0);
                Sc[mt][nt] = c;
            }
        }
        __builtin_amdgcn_s_setprio(0);

        // softmax numerator: P = 2^S directly (no max, no shuffles, no rescale)
        bf16x4 pb[4][2];
#pragma unroll
        for (int nt = 0; nt < 2; nt++) {
#pragma unroll
            for (int mt = 0; mt < 4; mt++) {
#pragma unroll
                for (int r = 0; r < 4; r++) Sc[mt][nt][r] = ex2(Sc[mt][nt][r]);
                union { u32 w2[2]; bf16x4 v; } pku;
                pku.w2[0] = pk2(Sc[mt][nt][0], Sc[mt][nt][1]);
                pku.w2[1] = pk2(Sc[mt][nt][2], Sc[mt][nt][3]);
                pb[mt][nt] = pku.v;
            }
        }

        __builtin_amdgcn_s_setprio(1);
        // l += colsum(P) via all-ones A-frag
#pragma unroll
        for (int nt = 0; nt < 2; nt++) {
            Ol[nt] = mfma16(onesb, pb[0][nt], Ol[nt]);
            Ol[nt] = mfma16(onesb, pb[1][nt], Ol[nt]);
            Ol[nt] = mfma16(onesb, pb[2][nt], Ol[nt]);
            Ol[nt] = mfma16(onesb, pb[3][nt], Ol[nt]);
        }

        // O^T += V^T·P^T : V-frag reads shared across both n-tiles
#pragma unroll
        for (int dt = 0; dt < 4; dt++) {
            const u16* vp = Vh + (dt * 16 + lm) * SP + quad * 16;
            bf16x8 v8a = *(const bf16x8*)vp;        // mt 0 (elems 0-3), mt 1 (4-7)
            bf16x8 v8b = *(const bf16x8*)(vp + 8);  // mt 2, mt 3
            bf16x4 va0 = __builtin_shufflevector(v8a, v8a, 0, 1, 2, 3);
            bf16x4 va1 = __builtin_shufflevector(v8a, v8a, 4, 5, 6, 7);
            bf16x4 va2 = __builtin_shufflevector(v8b, v8b, 0, 1, 2, 3);
            bf16x4 va3 = __builtin_shufflevector(v8b, v8b, 4, 5, 6, 7);
            O[dt][0] = mfma16(va0, pb[0][0], O[dt][0]);
            O[dt][1] = mfma16(va0, pb[0][1], O[dt][1]);
            O[dt][0] = mfma16(va1, pb[1][0], O[dt][0]);
            O[dt][1] = mfma16(va1, pb[1][1], O[dt][1]);
            O[dt][0] = mfma16(va2, pb[2][0], O[dt][0]);
            O[dt][1] = mfma16(va2, pb[2][1], O[dt][1]);
            O[dt][0] = mfma16(va3, pb[3][0], O[dt][0]);
            O[dt][1] = mfma16(va3, pb[3][1], O[dt][1]);
        }
        __builtin_amdgcn_s_setprio(0);

        // stage tile t+1 into the idle buffer; raw barrier keeps t+2 loads flying
        if (t + 1 < 16) {
            asm volatile("s_waitcnt vmcnt(0)" ::: "memory");  // t+1 loads (old) done
            WRBUF(cur ^ 1);
            if (t + 2 < 16) LOADT(t + 2);
        }
        asm volatile("s_waitcnt lgkmcnt(0)" ::: "memory");
        __builtin_amdgcn_s_barrier();
    }
#undef LOADT
#undef WRBUF

    // ---- in-block merge of the two key-halves through LDS (f32) ----
    // no-max: O = (O_A + O_B) / (l_A + l_B)
    float* obuf  = (float*)smem;           // [4 rg][64 lane][2 nt][16] = 32768B
    float* mlbuf = (float*)smem + 8192;    // [4 rg][64 lane][2 nt]     =  2048B
    if (w >= 4) {
#pragma unroll
        for (int nt = 0; nt < 2; nt++) {
            float* ob = obuf + (((rg * 64 + l) * 2 + nt) << 4);
#pragma unroll
            for (int dt = 0; dt < 4; dt++)
                *(floatx4*)(ob + dt * 4) = O[dt][nt];
            mlbuf[(rg * 64 + l) * 2 + nt] = Ol[nt][0];
        }
    }
    __syncthreads();
    if (w < 4) {
#pragma unroll
        for (int nt = 0; nt < 2; nt++) {
            float* ob = obuf + (((rg * 64 + l) * 2 + nt) << 4);
            float lB = mlbuf[(rg * 64 + l) * 2 + nt];
            float inv = 1.0f / (Ol[nt][0] + lB);
            int s = qt * 128 + rg * 32 + nt * 16 + lm;
            u16* op = out + ((size_t)b * SEQ + s) * DMODEL + h * DH;
#pragma unroll
            for (int dt = 0; dt < 4; dt++) {
                floatx4 Ob = *(const floatx4*)(ob + dt * 4);
                union { u32 w2[2]; u16x4 v; } pku;
                pku.w2[0] = pk2((O[dt][nt][0] + Ob[0]) * inv,
                                (O[dt][nt][1] + Ob[1]) * inv);
                pku.w2[1] = pk2((O[dt][nt][2] + Ob[2]) * inv,
                                (O[dt][nt][3] + Ob[3]) * inv);
                *(u16x4*)(op + dt * 16 + quad * 4) = pku.v;
            }
        }
    }
}

extern "C" void kernel_launch(void* const* d_in, const int* in_sizes, int n_in,
                              void* d_out, int out_size, void* d_ws, size_t ws_size,
                              hipStream_t stream) {
    (void)in_sizes; (void)n_in; (void)out_size;
    const float* Q  = (const float*)d_in[0];
    const float* K  = (const float*)d_in[1];
    const float* V  = (const float*)d_in[2];
    const float* Wq = (const float*)d_in[3];
    const float* bq = (const float*)d_in[4];
    const float* Wk = (const float*)d_in[5];
    const float* bk = (const float*)d_in[6];
    const float* Wv = (const float*)d_in[7];
    const float* bv = (const float*)d_in[8];
    const float* Wo = (const float*)d_in[9];
    const float* bo = (const float*)d_in[10];

    const size_t NEL = (size_t)2 * NH * SEQ * DH;  // 4,194,304 elements
    u16* base = (u16*)d_ws;
    dim3 bb(256);
    dim3 ab(512);

    if (ws_size >= 8 * NEL * 2) {
        u16* Qb   = base;
        u16* Kb   = Qb + NEL;
        u16* Vb   = Kb + NEL;
        u16* Wb   = Vb + NEL;
        u16* qws  = Wb + NEL;
        u16* kws  = qws + NEL;
        u16* vtws = kws + NEL;
        u16* aws  = vtws + NEL;
        cvt_all<<<dim3(2048, 7), bb, 0, stream>>>(Q, K, V, Wq, Wk, Wv, Wo, Qb, Kb, Vb, Wb);
        gemm_qkv_bb<<<dim3(8, 32, 3), bb, 0, stream>>>(
            Qb, Kb, Vb, Wb, bq, bk, bv, qws, kws, vtws);
        attn_kernel<<<dim3(SEQ / 128, 2 * NH), ab, 0, stream>>>(qws, kws, vtws, aws);
        gemm_o_p<<<dim3(16, 32), bb, 0, stream>>>(aws, Wb + 3145728, bo, (float*)d_out);
    } else if (ws_size >= 5 * NEL * 2) {
        u16* Wb = base;
        u16* qws = base + NEL; u16* kws = qws + NEL; u16* vtws = kws + NEL; u16* aws = vtws + NEL;
        cvt_w<<<dim3(512, 4), bb, 0, stream>>>(Wq, Wk, Wv, Wo, Wb);
        gemm_qkv<true><<<dim3(8, 32, 3), bb, 0, stream>>>(
            Q, K, V, Wb, Wb + 1048576, Wb + 2097152, bq, bk, bv, qws, kws, vtws);
        attn_kernel<<<dim3(SEQ / 128, 2 * NH), ab, 0, stream>>>(qws, kws, vtws, aws);
        gemm_o_p<<<dim3(16, 32), bb, 0, stream>>>(aws, Wb + 3145728, bo, (float*)d_out);
    } else {
        u16* qws = base; u16* kws = qws + NEL; u16* vtws = kws + NEL; u16* aws = vtws + NEL;
        gemm_qkv<false><<<dim3(8, 32, 3), bb, 0, stream>>>(
            Q, K, V, Wq, Wk, Wv, bq, bk, bv, qws, kws, vtws);
        attn_kernel<<<dim3(SEQ / 128, 2 * NH), ab, 0, stream>>>(qws, kws, vtws, aws);
        gemm_o<false><<<dim3(16, 32), bb, 0, stream>>>(aws, Wo, bo, (float*)d_out);
    }
}